// Round 3
// baseline (111.179 us; speedup 1.0000x reference)
//
#include <hip/hip_runtime.h>

#define B_SZ 16
#define T_SZ 512
#define D_SZ 384
#define MAX_DUR 8
#define OUT_LEN (T_SZ * (MAX_DUR - 1))   // 3584
#define D4 (D_SZ / 4)                    // 96
#define TOTAL4 (B_SZ * OUT_LEN * D4)     // 5,505,024
#define NWAVE (T_SZ / 64)                // 8
#define NPT 4
#define GBLK 256

typedef float vfloat4 __attribute__((ext_vector_type(4)));   // native vec for nt-store

// Kernel A: masked scan of ds via shfl wave-scan + cross-wave fixup, then
// SCATTER sidx[start..end) = t into LDS (inverse of searchsorted), then 7
// coalesced stores per thread. No Hillis-Steele barriers, no binary search.
__global__ void __launch_bounds__(T_SZ) scan_scatter_kernel(
    const int* __restrict__ ds,
    const int* __restrict__ ilens,
    int* __restrict__ idx_out)
{
    __shared__ int wsum[NWAVE];
    __shared__ int sidx[OUT_LEN];        // 14 KB
    const int b    = blockIdx.x;
    const int t    = threadIdx.x;
    const int lane = t & 63;
    const int w    = t >> 6;
    const int ilen = ilens[b];
    const int val  = (t < ilen) ? ds[b * T_SZ + t] : 0;

    // inclusive wave scan (64 lanes, 6 steps, no barriers)
    int x = val;
    #pragma unroll
    for (int off = 1; off < 64; off <<= 1) {
        int y = __shfl_up(x, off);
        if (lane >= off) x += y;
    }
    if (lane == 63) wsum[w] = x;
    __syncthreads();

    // cross-wave prefix + grand total (8 broadcast LDS reads)
    int prev = 0, tot = 0;
    #pragma unroll
    for (int i = 0; i < NWAVE; ++i) {
        int wsv = wsum[i];
        tot += wsv;
        if (i < w) prev += wsv;
    }
    const int end   = x + prev;          // inclusive csum[t]
    const int start = end - val;         // exclusive csum[t-1]

    // scatter: output rows [start, end) repeat source frame t  (<=7 iters)
    for (int r = start; r < end; ++r) sidx[r] = t;
    __syncthreads();

    // emit idx, -1 in the pad region (sidx there is uninitialized -> guarded)
    #pragma unroll
    for (int k = 0; k < OUT_LEN / T_SZ; ++k) {
        int o = k * T_SZ + t;
        idx_out[b * OUT_LEN + o] = (o < tot) ? sidx[o] : -1;
    }
}

// Kernel B: NPT float4 per thread, spaced GBLK apart (each access coalesced).
// Batched independent idx loads -> batched unconditional (clamped) xs loads
// -> select-zero -> nontemporal stores (out is write-once, keep L2 for xs).
static_assert(TOTAL4 % (GBLK * NPT) == 0, "grid must tile exactly");

__global__ void __launch_bounds__(GBLK) gather_kernel(
    const vfloat4* __restrict__ xs,
    const int* __restrict__ idx,
    vfloat4* __restrict__ out)
{
    const int base = blockIdx.x * (GBLK * NPT) + threadIdx.x;

    int g[NPT], row[NPT], d4v[NPT];
    #pragma unroll
    for (int j = 0; j < NPT; ++j) {
        g[j]   = base + j * GBLK;
        row[j] = g[j] / D4;              // magic-mul
        d4v[j] = g[j] - row[j] * D4;
    }

    int src[NPT];
    #pragma unroll
    for (int j = 0; j < NPT; ++j) src[j] = idx[row[j]];   // 4 independent loads

    vfloat4 v[NPT];
    #pragma unroll
    for (int j = 0; j < NPT; ++j) {
        int bb = row[j] / OUT_LEN;       // magic-mul
        int ii = src[j] < 0 ? 0 : src[j];        // clamp: pad rows read frame 0
        v[j] = xs[(bb * T_SZ + ii) * D4 + d4v[j]];        // 4 independent loads
    }

    #pragma unroll
    for (int j = 0; j < NPT; ++j) {
        vfloat4 zero = (vfloat4)0.0f;
        vfloat4 r = src[j] < 0 ? zero : v[j];
        __builtin_nontemporal_store(r, &out[g[j]]);
    }
}

extern "C" void kernel_launch(void* const* d_in, const int* in_sizes, int n_in,
                              void* d_out, int out_size, void* d_ws, size_t ws_size,
                              hipStream_t stream) {
    const float* xs    = (const float*)d_in[0];
    const int*   ds    = (const int*)d_in[1];
    const int*   ilens = (const int*)d_in[2];
    float*       out   = (float*)d_out;
    int*         idx   = (int*)d_ws;     // B*OUT_LEN ints = 229,376 bytes

    scan_scatter_kernel<<<B_SZ, T_SZ, 0, stream>>>(ds, ilens, idx);

    constexpr int nblk = TOTAL4 / (GBLK * NPT);   // 5376
    gather_kernel<<<nblk, GBLK, 0, stream>>>(
        (const vfloat4*)xs, idx, (vfloat4*)out);
}

// Round 4
// 109.538 us; speedup vs baseline: 1.0150x; 1.0150x over previous
//
#include <hip/hip_runtime.h>

#define B_SZ 16
#define T_SZ 512
#define D_SZ 384
#define MAX_DUR 8
#define OUT_LEN (T_SZ * (MAX_DUR - 1))     // 3584
#define D4 (D_SZ / 4)                      // 96
#define ROW4_PER_B (OUT_LEN * D4)          // 344064 float4 per batch
#define TOTAL4 (B_SZ * ROW4_PER_B)         // 5,505,024
#define BLK 256
#define NPT 4
#define F4_PER_BLK (BLK * NPT)             // 1024
#define BLK_PER_B (ROW4_PER_B / F4_PER_BLK)// 336
#define NBLK (B_SZ * BLK_PER_B)            // 5376
#define NWAVE (BLK / 64)                   // 4
#define MAXROWS 12                         // ceil((95+1024)/96) = 12 rows/block max

typedef float vfloat4 __attribute__((ext_vector_type(4)));

static_assert(ROW4_PER_B % F4_PER_BLK == 0, "block must not straddle batches");

// Single fused kernel. Each block:
//  1. redundantly computes its batch's masked inclusive csum (2KB ds, L2-hot)
//     via pair-per-thread shfl wave-scan + 4-wave LDS fixup,
//  2. binary-searches source frames for its <=12 output rows only,
//  3. streams its exactly-1024-float4 output slice (coalesced, nt-stores so
//     the write-once 88MB doesn't evict ds/xs from L2).
// No workspace, no second dispatch, no inter-kernel dependency stall.
__global__ void __launch_bounds__(BLK) fused_regularizer_kernel(
    const vfloat4* __restrict__ xs,
    const int* __restrict__ ds,
    const int* __restrict__ ilens,
    vfloat4* __restrict__ out)
{
    __shared__ int scsum[T_SZ];            // 2KB inclusive csum
    __shared__ int swsum[NWAVE];
    __shared__ int sfr[MAXROWS];           // source frame per covered row (-1 = pad)

    const int t        = threadIdx.x;
    const int lane     = t & 63;
    const int w        = t >> 6;
    const int batch    = blockIdx.x / BLK_PER_B;            // magic-mul
    const int blk_in_b = blockIdx.x - batch * BLK_PER_B;
    const int base4    = blk_in_b * F4_PER_BLK;             // float4 offset in batch

    // --- 1. masked pair-scan: thread t owns elements 2t, 2t+1 ---
    const int ilen = ilens[batch];
    const int p0 = 2 * t, p1 = 2 * t + 1;
    const int e0 = (p0 < ilen) ? ds[batch * T_SZ + p0] : 0;
    const int e1 = (p1 < ilen) ? ds[batch * T_SZ + p1] : 0;
    const int p  = e0 + e1;

    int x = p;                             // inclusive wave-scan of pair sums
    #pragma unroll
    for (int off = 1; off < 64; off <<= 1) {
        int y = __shfl_up(x, off);
        if (lane >= off) x += y;
    }
    if (lane == 63) swsum[w] = x;
    __syncthreads();

    int prev = 0, tot = 0;
    #pragma unroll
    for (int i = 0; i < NWAVE; ++i) {
        int v = swsum[i];
        tot += v;
        if (i < w) prev += v;
    }
    const int excl = x - p + prev;         // exclusive prefix of element 2t
    scsum[p0] = excl + e0;
    scsum[p1] = excl + e0 + e1;
    __syncthreads();

    // --- 2. source frame for the <=12 rows this block covers ---
    const int rstart = base4 / D4;
    const int rend   = (base4 + F4_PER_BLK - 1) / D4;
    if (t <= rend - rstart) {
        const int k = rstart + t;          // output row within batch
        int lo = 0, hi = T_SZ;             // first index with csum[lo] > k
        while (lo < hi) {
            int mid = (lo + hi) >> 1;
            if (scsum[mid] <= k) lo = mid + 1; else hi = mid;
        }
        int idx = lo < (T_SZ - 1) ? lo : (T_SZ - 1);
        sfr[t] = (k < tot) ? idx : -1;
    }
    __syncthreads();

    // --- 3. streaming copy of this block's 1024 float4 ---
    const vfloat4* __restrict__ xb = xs + (size_t)batch * T_SZ * D4;
    vfloat4* __restrict__ ob       = out + (size_t)batch * ROW4_PER_B + base4;

    #pragma unroll
    for (int j = 0; j < NPT; ++j) {
        const int g   = j * BLK + t;       // 0..1023 within slice
        const int gg  = base4 + g;
        const int row = gg / D4;           // magic-mul
        const int d4  = gg - row * D4;
        const int i   = sfr[row - rstart]; // LDS broadcast (row ~uniform per wave)
        vfloat4 v = xb[(i < 0 ? 0 : i) * D4 + d4];   // clamped, always in-bounds
        vfloat4 z = (vfloat4)0.0f;
        __builtin_nontemporal_store(i < 0 ? z : v, &ob[g]);
    }
}

extern "C" void kernel_launch(void* const* d_in, const int* in_sizes, int n_in,
                              void* d_out, int out_size, void* d_ws, size_t ws_size,
                              hipStream_t stream) {
    const vfloat4* xs  = (const vfloat4*)d_in[0];
    const int* ds      = (const int*)d_in[1];
    const int* ilens   = (const int*)d_in[2];
    vfloat4* out       = (vfloat4*)d_out;

    fused_regularizer_kernel<<<NBLK, BLK, 0, stream>>>(xs, ds, ilens, out);
}